// Round 1
// baseline (121.188 us; speedup 1.0000x reference)
//
#include <hip/hip_runtime.h>
#include <math.h>

// Problem constants (match reference)
#define NCURVES   256
#define GPER      64               // NUM_BEZIERS * NUM_SAMPLES = 2*32
#define NUM_G     (NCURVES*GPER)   // 16384
#define IMG_W     256
#define IMG_H     256
#define TILE      16
#define TILES_X   (IMG_W/TILE)     // 16
#define TILES_Y   (IMG_H/TILE)     // 16
#define NTILES    (TILES_X*TILES_Y)
#define REC_F     12               // floats per gaussian record (48 B, float4-aligned)

#define A_MIN     3.0e-6f          // alpha cutoff for tile bbox
#define P_CUT     (-12.6f)         // per-pixel power cutoff (consistent with A_MIN)
#define T_EPS     1.0e-5f          // transmittance early-out (GLOBAL T here -> err <= 1e-5)

#define WAVES     4                // waves per render block
#define GPW       (NUM_G/WAVES)    // 4096 gaussians scanned per wave
#define SCAN_B    16               // bbox values prefetched per lane per round

// ---------------------------------------------------------------------------
// Kernel 1 (prep): 256 blocks (curve) x 64 threads (gaussian sample).
// UNCHANGED from the verified 92.45us version: stable depth rank via wave
// reduction; conic/color/alpha; bezier mean; writes 48B record + packed tile
// bbox at sorted index gi = rank*64 + tid.
// record = {mx, my, A, B, C, alpha, cr, cg, cb, 0,0,0}
// ---------------------------------------------------------------------------
__global__ __launch_bounds__(GPER)
void prep(const float* __restrict__ ctrl,        // [256][10][2]
          const float* __restrict__ features,    // [256][3]
          const float* __restrict__ cholesky,    // [256][3]
          const float* __restrict__ opacity,     // [256]
          const float* __restrict__ depth,       // [256]
          float*       __restrict__ recs,        // [NUM_G][12]
          unsigned*    __restrict__ bbox)        // [NUM_G]
{
    int c   = blockIdx.x;
    int tid = threadIdx.x;          // 0..63 (exactly one wave)

    // ---- stable rank (matches stable argsort over 64x-repeated depths)
    float dc = depth[c];
    int r = 0;
    #pragma unroll
    for (int jj = 0; jj < 4; ++jj) {
        int j = tid + jj*64;
        float dj = depth[j];
        r += (dj < dc) || (dj == dc && j < c);
    }
    #pragma unroll
    for (int off = 32; off > 0; off >>= 1) r += __shfl_down(r, off, 64);
    r = __shfl(r, 0, 64);

    // ---- per-curve params (redundant across 64 lanes; L2-hot)
    float c0 = cholesky[3*c+0] + 0.5f;
    float c1 = cholesky[3*c+1];
    float c2 = cholesky[3*c+2] + 0.5f;
    float s00 = c0*c0;
    float s01 = c0*c1;
    float s11 = c1*c1 + c2*c2;
    float inv = 1.0f / (s00*s11 - s01*s01);
    float A  =  s11*inv;
    float Bc = -s01*inv;
    float Cc =  s00*inv;

    float cr = 1.0f/(1.0f + __expf(-features[3*c+0]));
    float cg = 1.0f/(1.0f + __expf(-features[3*c+1]));
    float cb = 1.0f/(1.0f + __expf(-features[3*c+2]));
    float al = 1.0f/(1.0f + __expf(-opacity[c]));

    float cut = fmaxf(2.0f*(__logf(al) - __logf(A_MIN)), 0.0f);
    float rx = sqrtf(cut * s00);
    float ry = sqrtf(cut * s11);

    // ---- bezier sample -> mean
    int k = tid >> 5;               // bezier segment 0/1
    int s = tid & 31;               // sample 0..31
    float t = 0.007f + (float)s * (0.986f/31.0f);
    float u = 1.0f - t;
    float t2=t*t, t3=t2*t, t4=t3*t, t5=t4*t;
    float u2=u*u, u3=u2*u, u4=u3*u, u5=u4*u;
    float w[6] = { u5, 5.0f*t*u4, 10.0f*t2*u3, 10.0f*t3*u2, 5.0f*t4*u, t5 };

    const float* cp = ctrl + c*20;
    float px = 0.0f, py = 0.0f;
    #pragma unroll
    for (int j = 0; j < 6; ++j) {
        int idx = (k*5 + j) % 10;   // seg0: 0..5 ; seg1: 5,6,7,8,9,0
        px += w[j]*cp[2*idx+0];
        py += w[j]*cp[2*idx+1];
    }
    float mx = (tanhf(px)*0.5f + 0.5f) * (float)IMG_W;
    float my = (tanhf(py)*0.5f + 0.5f) * (float)IMG_H;

    int gi = r*GPER + tid;          // depth-sorted gaussian index (stable ties)
    float* o = recs + (size_t)gi*REC_F;
    o[0]=mx; o[1]=my; o[2]=A; o[3]=Bc; o[4]=Cc; o[5]=al;
    o[6]=cr; o[7]=cg; o[8]=cb; o[9]=0.0f; o[10]=0.0f; o[11]=0.0f;

    int tx0 = min(max((int)floorf((mx - rx) * (1.0f/TILE)), 0), TILES_X-1);
    int tx1 = min(max((int)floorf((mx + rx) * (1.0f/TILE)), 0), TILES_X-1);
    int ty0 = min(max((int)floorf((my - ry) * (1.0f/TILE)), 0), TILES_Y-1);
    int ty1 = min(max((int)floorf((my + ry) * (1.0f/TILE)), 0), TILES_Y-1);
    bbox[gi] = (unsigned)tx0 | ((unsigned)ty0<<8) | ((unsigned)tx1<<16) | ((unsigned)ty1<<24);
}

// ---------------------------------------------------------------------------
// Kernel 2 (render_tile): UNSEGMENTED per-tile renderer. 256 blocks (= one
// per CU) x 256 threads (one per pixel of a 16x16 tile).
//
// Phase 1 (scan, ZERO barriers): wave w ballot-compacts the depth-ordered
//   gi range [w*4096, (w+1)*4096) into a wave-private LDS list. Ranges are
//   disjoint and ordered, so concat(list0..list3) is globally depth-ordered.
//   Capacity per wave = full range (4096 u16) -> overflow impossible.
// Phase 2 (composite): staged 256-wide chunks of the ordered list, GLOBAL
//   front-to-back alpha compositing with block-wide early-out once every
//   pixel has T < T_EPS (truncation error <= 1e-5 absolute). This is what
//   segmentation could never do: segments each restarted from T=1, so all
//   ~50k gaussian-tile pairs were always fully composited.
// Writes final pixels (+background, clamp) directly: the 16 MiB partial
// buffer and the combine kernel are gone.
// ---------------------------------------------------------------------------
__global__ __launch_bounds__(256)
void render_tile(const float*    __restrict__ recs,
                 const unsigned* __restrict__ bbox,
                 const float*    __restrict__ background,
                 float*          __restrict__ out)
{
    __shared__ unsigned short lst[WAVES][GPW];   // 32 KB: depth-ordered hit lists
    __shared__ float4   data[256][3];            // 12 KB: staged records
    __shared__ unsigned wn[WAVES];

    int tid   = threadIdx.x;
    int tile  = blockIdx.x;             // 0..255
    int tilex = tile & (TILES_X-1);
    int tiley = tile >> 4;

    int lane = tid & 63;
    int wid  = tid >> 6;
    unsigned long long lmask = (1ull << lane) - 1ull;

    // ---- Phase 1: wave-private ballot compaction over this wave's gi range.
    // SCAN_B independent loads in flight per round (1 wave/SIMD here, so
    // latency hiding must come from ILP, not TLP).
    int gbase = wid * GPW;
    int cnt = 0;                        // wave-uniform (ballot-derived)
    #pragma unroll 1
    for (int c = 0; c < GPW; c += 64*SCAN_B) {
        unsigned v[SCAN_B];
        #pragma unroll
        for (int u = 0; u < SCAN_B; ++u)
            v[u] = bbox[gbase + c + u*64 + lane];
        #pragma unroll
        for (int u = 0; u < SCAN_B; ++u) {
            unsigned b = v[u];
            int tx0 =  b        & 0xff;
            int ty0 = (b >> 8)  & 0xff;
            int tx1 = (b >> 16) & 0xff;
            int ty1 = (b >> 24) & 0xff;
            bool pred = (tilex >= tx0) & (tilex <= tx1) &
                        (tiley >= ty0) & (tiley <= ty1);
            unsigned long long m = __ballot(pred ? 1 : 0);
            if (pred)
                lst[wid][cnt + (int)__popcll(m & lmask)] =
                    (unsigned short)(c + u*64 + lane);
            cnt += (int)__popcll(m);
        }
    }
    if (lane == 0) wn[wid] = (unsigned)cnt;
    __syncthreads();                    // the scan's ONLY barrier

    unsigned n0 = wn[0], n1 = wn[1], n2 = wn[2], n3 = wn[3];
    int total = (int)(n0 + n1 + n2 + n3);

    float px = (float)(tilex*TILE + (tid & (TILE-1))) + 0.5f;
    float py = (float)(tiley*TILE + (tid >> 4)) + 0.5f;

    float T = 1.0f, accr = 0.0f, accg = 0.0f, accb = 0.0f;

    // ---- Phase 2: staged composite over the globally depth-ordered list.
    #pragma unroll 1
    for (int cb = 0; cb < total; cb += 256) {
        int k = cb + tid;
        if (k < total) {
            // locate (wave region, offset) for ordered entry k
            unsigned off = (unsigned)k; int w = 0;
            if (off >= n0) { off -= n0; w = 1;
              if (off >= n1) { off -= n1; w = 2;
                if (off >= n2) { off -= n2; w = 3; } } }
            int gi = w*GPW + (int)lst[w][off];
            const float4* rp = (const float4*)(recs + (size_t)gi*REC_F);
            float4 d0 = rp[0], d1 = rp[1], d2 = rp[2];
            data[tid][0] = d0;
            data[tid][1] = d1;
            data[tid][2] = d2;
        }
        // barrier publishes data[] AND evaluates global early-out
        int nalive = __syncthreads_count(T > T_EPS);
        if (nalive == 0) break;         // every pixel saturated: stop dead

        int n = min(256, total - cb);
        if (T > T_EPS) {
            for (int j = 0; j < n; ++j) {
                float4 q0 = data[j][0];         // mx, my, A, B
                float4 q1 = data[j][1];         // C, alpha, cr, cg
                float  cb_ = data[j][2].x;      // cb
                float dx = px - q0.x;
                float dy = py - q0.y;
                float p  = -0.5f*(q0.z*dx*dx + q1.x*dy*dy) - q0.w*dx*dy;
                if (p > P_CUT) {
                    float a = fminf(q1.y * __expf(p), 0.999f);
                    float wgt = a * T;
                    accr += wgt * q1.z;
                    accg += wgt * q1.w;
                    accb += wgt * cb_;
                    T *= (1.0f - a);
                    if (T < T_EPS) break;       // true global transmittance
                }
            }
        }
        __syncthreads();                // protect data[] reuse next chunk
    }

    // ---- final pixel: background + clamp, straight to output
    float r = fminf(fmaxf(accr + T*background[0], 0.0f), 1.0f);
    float g = fminf(fmaxf(accg + T*background[1], 0.0f), 1.0f);
    float b = fminf(fmaxf(accb + T*background[2], 0.0f), 1.0f);

    int X = tilex*TILE + (tid & (TILE-1));
    int Y = tiley*TILE + (tid >> 4);
    size_t oi = ((size_t)Y*IMG_W + X)*3;
    out[oi+0] = r;
    out[oi+1] = g;
    out[oi+2] = b;
}

// ---------------------------------------------------------------------------
extern "C" void kernel_launch(void* const* d_in, const int* in_sizes, int n_in,
                              void* d_out, int out_size, void* d_ws, size_t ws_size,
                              hipStream_t stream)
{
    const float* ctrl       = (const float*)d_in[0];  // (256,10,2)
    const float* features   = (const float*)d_in[1];  // (256,3)
    const float* cholesky   = (const float*)d_in[2];  // (256,3)
    const float* opacity    = (const float*)d_in[3];  // (256,1)
    const float* depth      = (const float*)d_in[4];  // (256,1)
    const float* background = (const float*)d_in[5];  // (3,)
    float* out = (float*)d_out;                       // (256,256,3)

    // workspace layout (16B-aligned); partial buffer eliminated
    char* w = (char*)d_ws;
    float*    recs  = (float*)   (w);                 // 786432 B
    unsigned* bboxp = (unsigned*)(w + 786432);        //  65536 B

    prep<<<NCURVES, GPER, 0, stream>>>(ctrl, features, cholesky, opacity, depth,
                                       recs, bboxp);
    render_tile<<<NTILES, 256, 0, stream>>>(recs, bboxp, background, out);
}

// Round 2
// 85.196 us; speedup vs baseline: 1.4225x; 1.4225x over previous
//
#include <hip/hip_runtime.h>
#include <math.h>

// Problem constants (match reference)
#define NCURVES   256
#define GPER      64               // NUM_BEZIERS * NUM_SAMPLES = 2*32
#define NUM_G     (NCURVES*GPER)   // 16384
#define IMG_W     256
#define IMG_H     256
#define TILE      16
#define TILES_X   (IMG_W/TILE)     // 16
#define TILES_Y   (IMG_H/TILE)     // 16
#define NTILES    (TILES_X*TILES_Y)
#define REC_F     12               // floats per gaussian record (48 B, float4-aligned)

#define A_MIN     3.0e-6f          // alpha cutoff for tile bbox
#define P_CUT     (-12.6f)         // per-pixel power cutoff (consistent with A_MIN)
#define T_EPS     1.0e-5f          // transmittance early-out (err <= 1e-5 per group)

#define SWAVES    16               // scan waves per block (= block waves)
#define GPW       (NUM_G/SWAVES)   // 1024 gaussians scanned per wave
#define QGRP      4                // depth groups compositing in parallel
#define CHUNK     64               // staged records per group chunk

// ---------------------------------------------------------------------------
// Kernel 1 (prep): UNCHANGED (verified). 256 blocks x 64 threads.
// record = {mx, my, A, B, C, alpha, cr, cg, cb, 0,0,0}
// ---------------------------------------------------------------------------
__global__ __launch_bounds__(GPER)
void prep(const float* __restrict__ ctrl,        // [256][10][2]
          const float* __restrict__ features,    // [256][3]
          const float* __restrict__ cholesky,    // [256][3]
          const float* __restrict__ opacity,     // [256]
          const float* __restrict__ depth,       // [256]
          float*       __restrict__ recs,        // [NUM_G][12]
          unsigned*    __restrict__ bbox)        // [NUM_G]
{
    int c   = blockIdx.x;
    int tid = threadIdx.x;          // 0..63 (exactly one wave)

    // ---- stable rank (matches stable argsort over 64x-repeated depths)
    float dc = depth[c];
    int r = 0;
    #pragma unroll
    for (int jj = 0; jj < 4; ++jj) {
        int j = tid + jj*64;
        float dj = depth[j];
        r += (dj < dc) || (dj == dc && j < c);
    }
    #pragma unroll
    for (int off = 32; off > 0; off >>= 1) r += __shfl_down(r, off, 64);
    r = __shfl(r, 0, 64);

    // ---- per-curve params (redundant across 64 lanes; L2-hot)
    float c0 = cholesky[3*c+0] + 0.5f;
    float c1 = cholesky[3*c+1];
    float c2 = cholesky[3*c+2] + 0.5f;
    float s00 = c0*c0;
    float s01 = c0*c1;
    float s11 = c1*c1 + c2*c2;
    float inv = 1.0f / (s00*s11 - s01*s01);
    float A  =  s11*inv;
    float Bc = -s01*inv;
    float Cc =  s00*inv;

    float cr = 1.0f/(1.0f + __expf(-features[3*c+0]));
    float cg = 1.0f/(1.0f + __expf(-features[3*c+1]));
    float cb = 1.0f/(1.0f + __expf(-features[3*c+2]));
    float al = 1.0f/(1.0f + __expf(-opacity[c]));

    float cut = fmaxf(2.0f*(__logf(al) - __logf(A_MIN)), 0.0f);
    float rx = sqrtf(cut * s00);
    float ry = sqrtf(cut * s11);

    // ---- bezier sample -> mean
    int k = tid >> 5;               // bezier segment 0/1
    int s = tid & 31;               // sample 0..31
    float t = 0.007f + (float)s * (0.986f/31.0f);
    float u = 1.0f - t;
    float t2=t*t, t3=t2*t, t4=t3*t, t5=t4*t;
    float u2=u*u, u3=u2*u, u4=u3*u, u5=u4*u;
    float w[6] = { u5, 5.0f*t*u4, 10.0f*t2*u3, 10.0f*t3*u2, 5.0f*t4*u, t5 };

    const float* cp = ctrl + c*20;
    float px = 0.0f, py = 0.0f;
    #pragma unroll
    for (int j = 0; j < 6; ++j) {
        int idx = (k*5 + j) % 10;   // seg0: 0..5 ; seg1: 5,6,7,8,9,0
        px += w[j]*cp[2*idx+0];
        py += w[j]*cp[2*idx+1];
    }
    float mx = (tanhf(px)*0.5f + 0.5f) * (float)IMG_W;
    float my = (tanhf(py)*0.5f + 0.5f) * (float)IMG_H;

    int gi = r*GPER + tid;          // depth-sorted gaussian index (stable ties)
    float* o = recs + (size_t)gi*REC_F;
    o[0]=mx; o[1]=my; o[2]=A; o[3]=Bc; o[4]=Cc; o[5]=al;
    o[6]=cr; o[7]=cg; o[8]=cb; o[9]=0.0f; o[10]=0.0f; o[11]=0.0f;

    int tx0 = min(max((int)floorf((mx - rx) * (1.0f/TILE)), 0), TILES_X-1);
    int tx1 = min(max((int)floorf((mx + rx) * (1.0f/TILE)), 0), TILES_X-1);
    int ty0 = min(max((int)floorf((my - ry) * (1.0f/TILE)), 0), TILES_Y-1);
    int ty1 = min(max((int)floorf((my + ry) * (1.0f/TILE)), 0), TILES_Y-1);
    bbox[gi] = (unsigned)tx0 | ((unsigned)ty0<<8) | ((unsigned)tx1<<16) | ((unsigned)ty1<<24);
}

// ---------------------------------------------------------------------------
// Kernel 2 (render_tile): per-tile renderer, 256 blocks x 1024 threads
// (16 waves -> 4 waves/SIMD: TLP that round 1 lacked).
//
// Phase 1 (scan, zero barriers): wave w ballot-compacts depth-ordered range
//   [w*1024,(w+1)*1024) into wave-private LDS list (full capacity: overflow
//   impossible). Concat of the 16 lists is globally depth-ordered.
// Phase 2 (composite, depth-parallel): alpha compositing is ASSOCIATIVE:
//   seg combine = {rgb0 + T0*rgb1, T0*T1}. 4 groups of 256 threads each
//   composite one ordered quarter of the hit list for all 256 pixels ->
//   the hot tile's serial chain drops 4x AND runs under 4-deep wave TLP.
//   Records are LDS-staged per group in [comp][entry] layout (contiguous
//   16B/lane writes -> conflict-free; consume reads are broadcasts).
// Phase 3: in-LDS front-to-back combine of 4 partials + background + clamp,
//   direct store. No partial buffer, no combine kernel.
// LDS: 32K lists + 12K stage + 16K partials = 61.5 KB.
// ---------------------------------------------------------------------------
__global__ __launch_bounds__(1024)
void render_tile(const float*    __restrict__ recs,
                 const unsigned* __restrict__ bbox,
                 const float*    __restrict__ background,
                 float*          __restrict__ out)
{
    __shared__ unsigned short lst[SWAVES][GPW];      // 32 KB
    __shared__ float4         data[QGRP][3][CHUNK];  // 12 KB, [comp][entry]
    __shared__ float4         part[QGRP][256];       // 16 KB
    __shared__ unsigned       wn[SWAVES];

    int tid   = threadIdx.x;
    int tile  = blockIdx.x;             // 0..255
    int tilex = tile & (TILES_X-1);
    int tiley = tile >> 4;

    int lane = tid & 63;
    int wid  = tid >> 6;                // 0..15
    unsigned long long lmask = (1ull << lane) - 1ull;

    // ---- Phase 1: wave-private ballot compaction (no barriers).
    {
        int gbase = wid * GPW;
        unsigned v[16];                 // 1024 = 64 lanes * 16 -> one batch
        #pragma unroll
        for (int u = 0; u < 16; ++u)
            v[u] = bbox[gbase + u*64 + lane];
        int cnt = 0;
        #pragma unroll
        for (int u = 0; u < 16; ++u) {
            unsigned b = v[u];
            bool pred = (tilex >= (int)( b        & 0xff)) &
                        (tilex <= (int)((b >> 16) & 0xff)) &
                        (tiley >= (int)((b >>  8) & 0xff)) &
                        (tiley <= (int)((b >> 24) & 0xff));
            unsigned long long m = __ballot(pred ? 1 : 0);
            if (pred)
                lst[wid][cnt + (int)__popcll(m & lmask)] =
                    (unsigned short)(u*64 + lane);
            cnt += (int)__popcll(m);
        }
        if (lane == 0) wn[wid] = (unsigned)cnt;
    }
    __syncthreads();

    // ---- prefix over the 16 wave counts (all static indexing -> registers)
    unsigned pref[SWAVES + 1];
    pref[0] = 0;
    #pragma unroll
    for (int i = 0; i < SWAVES; ++i) pref[i+1] = pref[i] + wn[i];
    int total = (int)pref[SWAVES];

    int q    = tid >> 8;                // depth group 0..3
    int pix  = tid & 255;               // pixel within tile
    int qstart = (total * q) >> 2;      // ordered quarter boundaries
    int qend   = (total * (q+1)) >> 2;
    int ncq    = qend - qstart;
    int maxq   = (total + 3) >> 2;
    int nch    = (maxq + CHUNK - 1) / CHUNK;   // uniform across groups

    float pxf = (float)(tilex*TILE + (pix & (TILE-1))) + 0.5f;
    float pyf = (float)(tiley*TILE + (pix >> 4)) + 0.5f;

    float T = 1.0f, accr = 0.0f, accg = 0.0f, accb = 0.0f;

    int comp = pix >> 6;                // staging role: component 0..3
    int e    = pix & 63;                // staging role: entry in chunk

    #pragma unroll 1
    for (int ch = 0; ch < nch; ++ch) {
        // ---- stage chunk ch of this group's quarter (threads 0..191 of group)
        if (comp < 3 && ch*CHUNK + e < ncq) {
            int k = qstart + ch*CHUNK + e;      // global ordered index
            // locate (wave region, offset); pref[] static -> stays in regs
            int w = 0; unsigned off = (unsigned)k;
            #pragma unroll
            for (int i = 1; i < SWAVES; ++i)
                if ((unsigned)k >= pref[i]) { w = i; off = (unsigned)k - pref[i]; }
            int gi = w*GPW + (int)lst[w][off];
            const float4* rp = (const float4*)(recs + (size_t)gi*REC_F);
            data[q][comp][e] = rp[comp];        // contiguous 16B/lane: no conflicts
        }
        __syncthreads();                        // chunk visible

        int n = ncq - ch*CHUNK;
        n = (n < 0) ? 0 : ((n > CHUNK) ? CHUNK : n);
        if (T > T_EPS) {
            for (int j = 0; j < n; ++j) {
                float4 q0  = data[q][0][j];     // mx, my, A, B  (broadcast)
                float4 q1  = data[q][1][j];     // C, alpha, cr, cg
                float  cb_ = data[q][2][j].x;   // cb
                float dx = pxf - q0.x;
                float dy = pyf - q0.y;
                float p  = -0.5f*(q0.z*dx*dx + q1.x*dy*dy) - q0.w*dx*dy;
                if (p > P_CUT) {
                    float a = fminf(q1.y * __expf(p), 0.999f);
                    float wgt = a * T;
                    accr += wgt * q1.z;
                    accg += wgt * q1.w;
                    accb += wgt * cb_;
                    T *= (1.0f - a);
                    if (T < T_EPS) break;       // group-local residual < 1e-5
                }
            }
        }
        __syncthreads();                        // protect data[] reuse
    }

    // ---- Phase 3: combine the 4 depth-ordered partials per pixel
    part[q][pix] = make_float4(accr, accg, accb, T);
    __syncthreads();

    if (tid < 256) {
        float4 a0 = part[0][tid];
        float4 a1 = part[1][tid];
        float4 a2 = part[2][tid];
        float4 a3 = part[3][tid];
        // front-to-back: rgb = r0 + T0*(r1 + T1*(r2 + T2*r3)); T = prod
        float r = a0.x + a0.w*(a1.x + a1.w*(a2.x + a2.w*a3.x));
        float g = a0.y + a0.w*(a1.y + a1.w*(a2.y + a2.w*a3.y));
        float b = a0.z + a0.w*(a1.z + a1.w*(a2.z + a2.w*a3.z));
        float Tt = a0.w * a1.w * a2.w * a3.w;

        r = fminf(fmaxf(r + Tt*background[0], 0.0f), 1.0f);
        g = fminf(fmaxf(g + Tt*background[1], 0.0f), 1.0f);
        b = fminf(fmaxf(b + Tt*background[2], 0.0f), 1.0f);

        int X = tilex*TILE + (tid & (TILE-1));
        int Y = tiley*TILE + (tid >> 4);
        size_t oi = ((size_t)Y*IMG_W + X)*3;
        out[oi+0] = r;
        out[oi+1] = g;
        out[oi+2] = b;
    }
}

// ---------------------------------------------------------------------------
extern "C" void kernel_launch(void* const* d_in, const int* in_sizes, int n_in,
                              void* d_out, int out_size, void* d_ws, size_t ws_size,
                              hipStream_t stream)
{
    const float* ctrl       = (const float*)d_in[0];  // (256,10,2)
    const float* features   = (const float*)d_in[1];  // (256,3)
    const float* cholesky   = (const float*)d_in[2];  // (256,3)
    const float* opacity    = (const float*)d_in[3];  // (256,1)
    const float* depth      = (const float*)d_in[4];  // (256,1)
    const float* background = (const float*)d_in[5];  // (3,)
    float* out = (float*)d_out;                       // (256,256,3)

    // workspace layout (16B-aligned)
    char* w = (char*)d_ws;
    float*    recs  = (float*)   (w);                 // 786432 B
    unsigned* bboxp = (unsigned*)(w + 786432);        //  65536 B

    prep<<<NCURVES, GPER, 0, stream>>>(ctrl, features, cholesky, opacity, depth,
                                       recs, bboxp);
    render_tile<<<NTILES, 1024, 0, stream>>>(recs, bboxp, background, out);
}

// Round 3
// 84.321 us; speedup vs baseline: 1.4372x; 1.0104x over previous
//
#include <hip/hip_runtime.h>
#include <hip/hip_fp16.h>
#include <math.h>

// Problem constants (match reference)
#define NCURVES   256
#define GPER      64               // NUM_BEZIERS * NUM_SAMPLES = 2*32
#define NUM_G     (NCURVES*GPER)   // 16384
#define IMG_W     256
#define IMG_H     256
#define TILE      16
#define TILES_X   (IMG_W/TILE)     // 16
#define TILES_Y   (IMG_H/TILE)     // 16
#define NTILES    (TILES_X*TILES_Y)
#define REC_F     8                // floats per gaussian record (32 B: 2 float4)

#define A_MIN     3.0e-6f          // alpha cutoff for tile bbox
#define P_CUT     (-12.6f)         // per-pixel power cutoff (consistent with A_MIN)

#define SEGS      8                // depth slices (by gi range) -> cross-CU split
#define GSEG      (NUM_G/SEGS)     // 2048 gaussians per slice
#define GWAVE     (GSEG/4)         // 512 per scan wave (4 waves/block)

// ---------------------------------------------------------------------------
// Kernel 1 (prep): 256 blocks x 64 threads. Same verified math as before;
// record now packed to 8 floats: {mx,my,A,B},{C,alpha,rg(f16x2),cb(f16)}.
// Colors in f16: weights sum <= 1 -> added error <= 5e-4, well under tol.
// ---------------------------------------------------------------------------
__global__ __launch_bounds__(GPER)
void prep(const float* __restrict__ ctrl,        // [256][10][2]
          const float* __restrict__ features,    // [256][3]
          const float* __restrict__ cholesky,    // [256][3]
          const float* __restrict__ opacity,     // [256]
          const float* __restrict__ depth,       // [256]
          float*       __restrict__ recs,        // [NUM_G][8]
          unsigned*    __restrict__ bbox)        // [NUM_G]
{
    int c   = blockIdx.x;
    int tid = threadIdx.x;          // 0..63 (exactly one wave)

    // ---- stable rank (matches stable argsort over 64x-repeated depths)
    float dc = depth[c];
    int r = 0;
    #pragma unroll
    for (int jj = 0; jj < 4; ++jj) {
        int j = tid + jj*64;
        float dj = depth[j];
        r += (dj < dc) || (dj == dc && j < c);
    }
    #pragma unroll
    for (int off = 32; off > 0; off >>= 1) r += __shfl_down(r, off, 64);
    r = __shfl(r, 0, 64);

    // ---- per-curve params
    float c0 = cholesky[3*c+0] + 0.5f;
    float c1 = cholesky[3*c+1];
    float c2 = cholesky[3*c+2] + 0.5f;
    float s00 = c0*c0;
    float s01 = c0*c1;
    float s11 = c1*c1 + c2*c2;
    float inv = 1.0f / (s00*s11 - s01*s01);
    float A  =  s11*inv;
    float Bc = -s01*inv;
    float Cc =  s00*inv;

    float cr = 1.0f/(1.0f + __expf(-features[3*c+0]));
    float cg = 1.0f/(1.0f + __expf(-features[3*c+1]));
    float cb = 1.0f/(1.0f + __expf(-features[3*c+2]));
    float al = 1.0f/(1.0f + __expf(-opacity[c]));

    float cut = fmaxf(2.0f*(__logf(al) - __logf(A_MIN)), 0.0f);
    float rx = sqrtf(cut * s00);
    float ry = sqrtf(cut * s11);

    // ---- bezier sample -> mean
    int k = tid >> 5;               // bezier segment 0/1
    int s = tid & 31;               // sample 0..31
    float t = 0.007f + (float)s * (0.986f/31.0f);
    float u = 1.0f - t;
    float t2=t*t, t3=t2*t, t4=t3*t, t5=t4*t;
    float u2=u*u, u3=u2*u, u4=u3*u, u5=u4*u;
    float w[6] = { u5, 5.0f*t*u4, 10.0f*t2*u3, 10.0f*t3*u2, 5.0f*t4*u, t5 };

    const float* cp = ctrl + c*20;
    float px = 0.0f, py = 0.0f;
    #pragma unroll
    for (int j = 0; j < 6; ++j) {
        int idx = (k*5 + j) % 10;   // seg0: 0..5 ; seg1: 5,6,7,8,9,0
        px += w[j]*cp[2*idx+0];
        py += w[j]*cp[2*idx+1];
    }
    float mx = (tanhf(px)*0.5f + 0.5f) * (float)IMG_W;
    float my = (tanhf(py)*0.5f + 0.5f) * (float)IMG_H;

    int gi = r*GPER + tid;          // depth-sorted gaussian index (stable ties)

    unsigned rg  = (unsigned)__half_as_ushort(__float2half_rn(cr))
                 | ((unsigned)__half_as_ushort(__float2half_rn(cg)) << 16);
    unsigned cbp = (unsigned)__half_as_ushort(__float2half_rn(cb));

    float4* o4 = (float4*)(recs + (size_t)gi*REC_F);
    o4[0] = make_float4(mx, my, A, Bc);
    o4[1] = make_float4(Cc, al, __uint_as_float(rg), __uint_as_float(cbp));

    int tx0 = min(max((int)floorf((mx - rx) * (1.0f/TILE)), 0), TILES_X-1);
    int tx1 = min(max((int)floorf((mx + rx) * (1.0f/TILE)), 0), TILES_X-1);
    int ty0 = min(max((int)floorf((my - ry) * (1.0f/TILE)), 0), TILES_Y-1);
    int ty1 = min(max((int)floorf((my + ry) * (1.0f/TILE)), 0), TILES_Y-1);
    bbox[gi] = (unsigned)tx0 | ((unsigned)ty0<<8) | ((unsigned)tx1<<16) | ((unsigned)ty1<<24);
}

// ---------------------------------------------------------------------------
// Kernel 2 (render8): grid = (tile, gi-eighth) = 2048 blocks x 256 threads.
// The hot tile's depth chain is split across 8 DIFFERENT CUs (round 2 put
// all 16 waves of the hot tile on one CU -> 22 us). Total scan work is
// invariant under the split (NTILES*NUM_G tests).
//
// Phase 1: two-pass ballot scan of this block's 2048-gi slice into a flat
//   depth-ordered u16 list in LDS (4 waves, wave-private subranges; concat
//   is ordered; capacity = full slice -> overflow impossible).
// Phase 2: all 256 threads (pixels) walk the list, reading 32B records
//   straight from L2 (wave-broadcast addresses; 25k pairs x 32B ~ 800KB,
//   L2-resident -> LDS staging + its barriers were pure overhead).
// Writes one float4 partial per pixel; slice boundaries at fixed gi are
// depth-contiguous -> associative combine in kernel 3 is exact.
// ---------------------------------------------------------------------------
__global__ __launch_bounds__(256)
void render8(const float*    __restrict__ recs,
             const unsigned* __restrict__ bbox,
             float4*         __restrict__ partial)   // [SEGS][IMG_H*IMG_W]
{
    __shared__ unsigned short flat[GSEG];   // 4 KB: ordered hit list (gi-local)
    __shared__ unsigned       wn[4];

    int tid   = threadIdx.x;
    int seg   = blockIdx.x & (SEGS-1);
    int tile  = blockIdx.x >> 3;            // 0..255
    int tilex = tile & (TILES_X-1);
    int tiley = tile >> 4;

    int lane = tid & 63;
    int wid  = tid >> 6;                    // 0..3
    unsigned long long lmask = (1ull << lane) - 1ull;

    int sbase = seg * GSEG;
    int gwave = wid * GWAVE;                // local base of this wave's subrange

    // ---- Phase 1a: predicate + count (no LDS writes yet)
    bool pr[8];
    int cnt = 0;
    {
        unsigned bb[8];
        #pragma unroll
        for (int u = 0; u < 8; ++u)
            bb[u] = bbox[sbase + gwave + u*64 + lane];
        #pragma unroll
        for (int u = 0; u < 8; ++u) {
            unsigned b = bb[u];
            pr[u] = (tilex >= (int)( b        & 0xff)) &
                    (tilex <= (int)((b >> 16) & 0xff)) &
                    (tiley >= (int)((b >>  8) & 0xff)) &
                    (tiley <= (int)((b >> 24) & 0xff));
            cnt += (int)__popcll(__ballot(pr[u] ? 1 : 0));
        }
    }
    if (lane == 0) wn[wid] = (unsigned)cnt;
    __syncthreads();

    unsigned p1 = wn[0], p2 = p1 + wn[1], p3 = p2 + wn[2];
    int total = (int)(p3 + wn[3]);

    // ---- Phase 1b: compact into flat ordered list
    if (total) {
        unsigned base = (wid == 0) ? 0u : (wid == 1) ? p1 : (wid == 2) ? p2 : p3;
        int off = 0;
        #pragma unroll
        for (int u = 0; u < 8; ++u) {
            unsigned long long m = __ballot(pr[u] ? 1 : 0);
            if (pr[u])
                flat[base + off + (int)__popcll(m & lmask)] =
                    (unsigned short)(gwave + u*64 + lane);
            off += (int)__popcll(m);
        }
    }
    __syncthreads();

    // ---- Phase 2: composite straight from L2 (broadcast reads, no staging)
    int ix = tid & (TILE-1);
    int iy = tid >> 4;
    float pxf = (float)(tilex*TILE + ix) + 0.5f;
    float pyf = (float)(tiley*TILE + iy) + 0.5f;

    float T = 1.0f, accr = 0.0f, accg = 0.0f, accb = 0.0f;

    #pragma unroll 2
    for (int j = 0; j < total; ++j) {
        int gl = (int)flat[j];                              // LDS broadcast
        const float4* rp = (const float4*)(recs + (size_t)(sbase + gl)*REC_F);
        float4 r0 = rp[0];          // mx, my, A, B   (wave-broadcast, L2)
        float4 r1 = rp[1];          // C, alpha, rg(f16x2), cb(f16)
        float dx = pxf - r0.x;
        float dy = pyf - r0.y;
        float p  = -0.5f*(r0.z*dx*dx + r1.x*dy*dy) - r0.w*dx*dy;
        if (p > P_CUT) {
            float a = fminf(r1.y * __expf(p), 0.999f);
            float wgt = a * T;
            unsigned rg = __float_as_uint(r1.z);
            accr += wgt * __half2float(__ushort_as_half((unsigned short)(rg & 0xffff)));
            accg += wgt * __half2float(__ushort_as_half((unsigned short)(rg >> 16)));
            accb += wgt * __half2float(__ushort_as_half((unsigned short)__float_as_uint(r1.w)));
            T *= (1.0f - a);
        }
    }

    int X = tilex*TILE + ix;
    int Y = tiley*TILE + iy;
    partial[(size_t)seg*(IMG_W*IMG_H) + (size_t)Y*IMG_W + X] =
        make_float4(accr, accg, accb, T);
}

// ---------------------------------------------------------------------------
// Kernel 3: combine the 8 depth-ordered slices front-to-back, + background,
// clamp, store. 8 MB read (mostly L2/HBM ~1.5us), 768 KB write.
// ---------------------------------------------------------------------------
__global__ __launch_bounds__(256)
void combine(const float4* __restrict__ partial,
             const float*  __restrict__ background,
             float*        __restrict__ out)
{
    int p = blockIdx.x * 256 + threadIdx.x;     // pixel 0..65535

    float accr = 0.0f, accg = 0.0f, accb = 0.0f, T = 1.0f;
    #pragma unroll
    for (int s = 0; s < SEGS; ++s) {
        float4 q = partial[(size_t)s*(IMG_W*IMG_H) + p];
        accr += T * q.x;
        accg += T * q.y;
        accb += T * q.z;
        T    *= q.w;
    }
    float r = fminf(fmaxf(accr + T*background[0], 0.0f), 1.0f);
    float g = fminf(fmaxf(accg + T*background[1], 0.0f), 1.0f);
    float b = fminf(fmaxf(accb + T*background[2], 0.0f), 1.0f);

    size_t oi = (size_t)p*3;
    out[oi+0] = r;
    out[oi+1] = g;
    out[oi+2] = b;
}

// ---------------------------------------------------------------------------
extern "C" void kernel_launch(void* const* d_in, const int* in_sizes, int n_in,
                              void* d_out, int out_size, void* d_ws, size_t ws_size,
                              hipStream_t stream)
{
    const float* ctrl       = (const float*)d_in[0];  // (256,10,2)
    const float* features   = (const float*)d_in[1];  // (256,3)
    const float* cholesky   = (const float*)d_in[2];  // (256,3)
    const float* opacity    = (const float*)d_in[3];  // (256,1)
    const float* depth      = (const float*)d_in[4];  // (256,1)
    const float* background = (const float*)d_in[5];  // (3,)
    float* out = (float*)d_out;                       // (256,256,3)

    // workspace layout (16B-aligned)
    char* w = (char*)d_ws;
    float*    recs    = (float*)   (w);                    // 524288 B
    unsigned* bboxp   = (unsigned*)(w + 524288);           //  65536 B
    float4*   partial = (float4*)  (w + 524288 + 65536);   // 8 MiB

    prep<<<NCURVES, GPER, 0, stream>>>(ctrl, features, cholesky, opacity, depth,
                                       recs, bboxp);
    render8<<<NTILES*SEGS, 256, 0, stream>>>(recs, bboxp, partial);
    combine<<<(IMG_W*IMG_H)/256, 256, 0, stream>>>(partial, background, out);
}